// Round 5
// baseline (944.241 us; speedup 1.0000x reference)
//
#include <hip/hip_runtime.h>
#include <stdint.h>

// GLRU associative scan — single-pass decoupled lookback (R5: fix ref-binding).
// B=4, T=4096, D=1024. x[b][t][3072] = [inp | input_gate | output_gate] raw.
// h_t = a_t*h_{t-1} + b_t; a = 1-sig(xg); b = tanh(xi)*sig(xg); h_{-1}=carry.
// y_t = tanh(h_t)*sig(xo). Outputs: h_last (4096 floats) then y (16.7M floats).
//
// Grid = CHUNKS*B = 1024 blocks @ __launch_bounds__(256,4) -> 4 blocks/CU on
// 256 CUs = all blocks co-resident -> lookback cannot deadlock.

#define B_SZ 4
#define T_LEN 4096
#define DH 1024
#define ROW4 (3 * DH / 4)      // 768 float4 per (b,t) row
#define CHUNKS 256
#define CLEN (T_LEN / CHUNKS)  // 16

#define FLAG_AGG 1u
#define FLAG_INC 2u

typedef float vf4 __attribute__((ext_vector_type(4)));

__device__ __forceinline__ float fsig(float v) {
    return __builtin_amdgcn_rcpf(1.0f + __expf(-v));
}
__device__ __forceinline__ float ftanh(float v) {
    return 1.0f - 2.0f * __builtin_amdgcn_rcpf(__expf(2.0f * v) + 1.0f);
}
__device__ __forceinline__ vf4 sig4(vf4 v) {
    vf4 r; r.x = fsig(v.x); r.y = fsig(v.y); r.z = fsig(v.z); r.w = fsig(v.w); return r;
}
__device__ __forceinline__ vf4 tanh4(vf4 v) {
    vf4 r; r.x = ftanh(v.x); r.y = ftanh(v.y); r.z = ftanh(v.z); r.w = ftanh(v.w); return r;
}
struct F2 { float a, b; };
__device__ __forceinline__ uint64_t pack2(float a, float b) {
    union { float f[2]; uint64_t u; } u; u.f[0] = a; u.f[1] = b; return u.u;
}
__device__ __forceinline__ F2 unpack2(uint64_t v) {
    union { uint64_t u; float f[2]; } u; u.u = v; return {u.f[0], u.f[1]};
}

// ws is poisoned 0xAA before every timed launch (0xAAAAAAAA is neither AGG nor
// INC), but first-call state is unknown -> explicit zero of flags each launch.
__global__ __launch_bounds__(256) void glru_flags_init(uint32_t* __restrict__ flags) {
    const int i = blockIdx.x * 256 + threadIdx.x;
    if (i < B_SZ * CHUNKS) flags[i] = 0u;
}

__global__ __launch_bounds__(256, 4) void glru_fused(
    const float* __restrict__ x, const float* __restrict__ carry,
    uint64_t* __restrict__ AB,     // [B][CHUNKS][DH]   packed (A,B) per channel
    uint64_t* __restrict__ Hp,     // [B][CHUNKS][DH/2] packed inclusive h pairs
    uint32_t* __restrict__ flags,  // [B][CHUNKS]
    float* __restrict__ hlast,     // [B][DH]
    float* __restrict__ y)         // [B][T][DH]
{
    const int c = blockIdx.x & (CHUNKS - 1);
    const int b = blockIdx.x >> 8;
    const int d4 = threadIdx.x;  // 4 channels: 4*d4 .. 4*d4+3
    const vf4* base = (const vf4*)x + (size_t)(b * T_LEN + c * CLEN) * ROW4;
    const size_t fb = (size_t)b * CHUNKS;

    // ---- phase A: local chunk aggregate (A, B) with h_in = 0 ----
    vf4 A = {1.f, 1.f, 1.f, 1.f};
    vf4 Bv = {0.f, 0.f, 0.f, 0.f};
    #pragma unroll 4
    for (int t = 0; t < CLEN; ++t) {
        vf4 vi = base[(size_t)t * ROW4 + d4];
        vf4 vg = base[(size_t)t * ROW4 + 256 + d4];
        vf4 ig = sig4(vg);
        vf4 a = 1.f - ig;
        A *= a;
        Bv = a * Bv + tanh4(vi) * ig;
    }

    vf4 hin;
    if (c == 0) {
        hin = ((const vf4*)carry)[b * 256 + d4];
    } else {
        // publish AGGREGATE
        uint64_t* ab = AB + (fb + c) * DH + (size_t)d4 * 4;
        __hip_atomic_store(&ab[0], pack2(A.x, Bv.x), __ATOMIC_RELAXED, __HIP_MEMORY_SCOPE_AGENT);
        __hip_atomic_store(&ab[1], pack2(A.y, Bv.y), __ATOMIC_RELAXED, __HIP_MEMORY_SCOPE_AGENT);
        __hip_atomic_store(&ab[2], pack2(A.z, Bv.z), __ATOMIC_RELAXED, __HIP_MEMORY_SCOPE_AGENT);
        __hip_atomic_store(&ab[3], pack2(A.w, Bv.w), __ATOMIC_RELAXED, __HIP_MEMORY_SCOPE_AGENT);
        __syncthreads();
        if (threadIdx.x == 0)
            __hip_atomic_store(&flags[fb + c], FLAG_AGG, __ATOMIC_RELEASE, __HIP_MEMORY_SCOPE_AGENT);

        // ---- decoupled lookback (per-thread, independent channels) ----
        vf4 Ax = {1.f, 1.f, 1.f, 1.f};
        vf4 Bx = {0.f, 0.f, 0.f, 0.f};
        int j = c - 1;
        for (;;) {
            uint32_t f = __hip_atomic_load(&flags[fb + j], __ATOMIC_ACQUIRE, __HIP_MEMORY_SCOPE_AGENT);
            if (f == FLAG_INC) {
                const uint64_t* hp = Hp + (fb + j) * (DH / 2) + (size_t)d4 * 2;
                uint64_t p0 = __hip_atomic_load(&hp[0], __ATOMIC_RELAXED, __HIP_MEMORY_SCOPE_AGENT);
                uint64_t p1 = __hip_atomic_load(&hp[1], __ATOMIC_RELAXED, __HIP_MEMORY_SCOPE_AGENT);
                F2 u0 = unpack2(p0), u1 = unpack2(p1);
                vf4 hj = {u0.a, u0.b, u1.a, u1.b};
                hin = Ax * hj + Bx;
                break;
            } else if (f == FLAG_AGG) {
                const uint64_t* abj = AB + (fb + j) * DH + (size_t)d4 * 4;
                uint64_t q0 = __hip_atomic_load(&abj[0], __ATOMIC_RELAXED, __HIP_MEMORY_SCOPE_AGENT);
                uint64_t q1 = __hip_atomic_load(&abj[1], __ATOMIC_RELAXED, __HIP_MEMORY_SCOPE_AGENT);
                uint64_t q2 = __hip_atomic_load(&abj[2], __ATOMIC_RELAXED, __HIP_MEMORY_SCOPE_AGENT);
                uint64_t q3 = __hip_atomic_load(&abj[3], __ATOMIC_RELAXED, __HIP_MEMORY_SCOPE_AGENT);
                F2 w0 = unpack2(q0), w1 = unpack2(q1), w2 = unpack2(q2), w3 = unpack2(q3);
                vf4 Aj = {w0.a, w1.a, w2.a, w3.a};
                vf4 Bj = {w0.b, w1.b, w2.b, w3.b};
                Bx = Ax * Bj + Bx;   // prepend chunk j to composition (j..c-1)
                Ax = Ax * Aj;
                --j;                 // j>=0 always: chunk 0 publishes INC directly
            } else {
                __builtin_amdgcn_s_sleep(2);
            }
        }
    }

    // ---- publish INCLUSIVE h at end of this chunk ----
    vf4 hend = A * hin + Bv;
    {
        uint64_t* hp = Hp + (fb + c) * (DH / 2) + (size_t)d4 * 2;
        __hip_atomic_store(&hp[0], pack2(hend.x, hend.y), __ATOMIC_RELAXED, __HIP_MEMORY_SCOPE_AGENT);
        __hip_atomic_store(&hp[1], pack2(hend.z, hend.w), __ATOMIC_RELAXED, __HIP_MEMORY_SCOPE_AGENT);
        __syncthreads();
        if (threadIdx.x == 0)
            __hip_atomic_store(&flags[fb + c], FLAG_INC, __ATOMIC_RELEASE, __HIP_MEMORY_SCOPE_AGENT);
    }
    if (c == CHUNKS - 1) ((vf4*)hlast)[b * 256 + d4] = hend;

    // ---- phase B: replay chunk from hin, write y (nontemporal) ----
    vf4* yb = (vf4*)y + (size_t)(b * T_LEN + c * CLEN) * 256;
    vf4 h = hin;
    #pragma unroll 2
    for (int t = 0; t < CLEN; ++t) {
        vf4 vi = base[(size_t)t * ROW4 + d4];
        vf4 vg = base[(size_t)t * ROW4 + 256 + d4];
        vf4 vo = base[(size_t)t * ROW4 + 512 + d4];
        vf4 ig = sig4(vg);
        vf4 a = 1.f - ig;
        h = a * h + tanh4(vi) * ig;
        vf4 out = tanh4(h) * sig4(vo);
        __builtin_nontemporal_store(out, &yb[(size_t)t * 256 + d4]);
    }
}

extern "C" void kernel_launch(void* const* d_in, const int* in_sizes, int n_in,
                              void* d_out, int out_size, void* d_ws, size_t ws_size,
                              hipStream_t stream) {
    const float* x = (const float*)d_in[0];      // (4, 4096, 3072) fp32
    const float* carry = (const float*)d_in[1];  // (4, 1024) fp32

    float* hlast = (float*)d_out;                // output 0: (4,1024)
    float* y = (float*)d_out + B_SZ * DH;        // output 1: (4,4096,1024)

    // ws: AB (8 MB) + Hp (4 MB) + flags (4 KB)
    uint64_t* AB = (uint64_t*)d_ws;
    uint64_t* Hp = AB + (size_t)B_SZ * CHUNKS * DH;
    uint32_t* flags = (uint32_t*)(Hp + (size_t)B_SZ * CHUNKS * (DH / 2));

    glru_flags_init<<<4, 256, 0, stream>>>(flags);
    glru_fused<<<B_SZ * CHUNKS, 256, 0, stream>>>(x, carry, AB, Hp, flags, hlast, y);
}